// Round 4
// baseline (258.175 us; speedup 1.0000x reference)
//
#include <hip/hip_runtime.h>
#include <climits>

#define B   8192
#define D   256
#define TOT 16384
#define GS  16
#define NC  (GS * GS * GS)   // 4096 cells
#define JC2 256

// ---------------- workspace layout (bytes) ----------------
// sorted_pts4 : f32x4 [B]   @ 0        (131072)
// sorted_idx  : i32  [B]    @ 131072   (32768)
// cnt         : i32  [NC]   @ 163840   (16384)
// start       : i32  [NC]   @ 180224   (16384)
// cursor      : i32  [NC]   @ 196608   (16384)
// invn        : f64  [TOT]  @ 212992   (131072)
// S_part      : f64  [65536]@ 344064   (524288)
// S           : f64  [256]  @ 868352   (2048)
// comb        : f64  [TOT]  @ 870400   (131072)
// rank        : i32  [TOT]  @ 1001472  (65536)
// total ~1.07 MB

__device__ __forceinline__ int clamp_cell(float x) {
    int c = (int)(x * (float)GS);
    if (c < 0) c = 0;
    if (c > GS - 1) c = GS - 1;
    return c;
}

// G0: zero cell counts
__global__ void zero_cnt(int* __restrict__ cnt) {
    cnt[blockIdx.x * 256 + threadIdx.x] = 0;
}

// G1: histogram of cell ids
__global__ void grid_hist(const float* __restrict__ ref, int* __restrict__ cnt) {
    int i = blockIdx.x * 256 + threadIdx.x;
    int cx = clamp_cell(ref[i * 3 + 0]);
    int cy = clamp_cell(ref[i * 3 + 1]);
    int cz = clamp_cell(ref[i * 3 + 2]);
    atomicAdd(&cnt[(cz * GS + cy) * GS + cx], 1);
}

// G2: exclusive scan of 4096 counts -> start[], cursor[]  (single block, 256 thr)
__global__ void grid_scan(const int* __restrict__ cnt, int* __restrict__ start,
                          int* __restrict__ cursor) {
    __shared__ int part[256];
    int t = threadIdx.x;
    int s = 0;
    for (int k = 0; k < 16; ++k) s += cnt[t * 16 + k];
    part[t] = s;
    __syncthreads();
    if (t == 0) {
        int acc = 0;
        for (int q = 0; q < 256; ++q) { int v = part[q]; part[q] = acc; acc += v; }
    }
    __syncthreads();
    int base = part[t];
    for (int k = 0; k < 16; ++k) {
        int c = t * 16 + k;
        int v = cnt[c];
        start[c] = base; cursor[c] = base;
        base += v;
    }
}

// G3: scatter points into cell-sorted order, precompute sq = (x*x+y*y)+z*z (ref-exact)
__global__ void grid_scatter(const float* __restrict__ ref, int* __restrict__ cursor,
                             float4* __restrict__ sorted_pts4, int* __restrict__ sorted_idx) {
    int i = blockIdx.x * 256 + threadIdx.x;
    float x = ref[i * 3 + 0], y = ref[i * 3 + 1], z = ref[i * 3 + 2];
    int c = (clamp_cell(z) * GS + clamp_cell(y)) * GS + clamp_cell(x);
    float sq = __fadd_rn(__fadd_rn(__fmul_rn(x, x), __fmul_rn(y, y)), __fmul_rn(z, z));
    int pos = atomicAdd(&cursor[c], 1);
    sorted_pts4[pos] = make_float4(x, y, z, sq);
    sorted_idx[pos]  = i;
}

// G4: grid kNN. Thread k handles the k-th cell-sorted point (cache-coherent queries).
// Examined pairs use the EXACT verified f32 reference sequence:
//   dot = fma(qz,pz, fma(qy,py, qx*px)); d2 = (qsq+psq) - 2*dot; d = sqrt_rn(max(d2,0)).
// Ring invariant: after scanning the (2R+1)^3 block, every unexamined j has true
// distance > R*h. Stop when 3 found and b2 < R*h - 1e-3 (>> ref-d rounding error),
// so no unexamined point can enter the top-3 => identical to the full O(N^2) scan.
__global__ void knn_grid(const float4* __restrict__ sorted_pts4, const int* __restrict__ sorted_idx,
                         const int* __restrict__ start, const int* __restrict__ cnt,
                         float* __restrict__ out_closest) {
    int k = blockIdx.x * 256 + threadIdx.x;
    float4 q = sorted_pts4[k];
    int i = sorted_idx[k];
    int cx = clamp_cell(q.x), cy = clamp_cell(q.y), cz = clamp_cell(q.z);
    float b0 = INFINITY, b1 = INFINITY, b2 = INFINITY;
    int   i0 = INT_MAX, i1 = INT_MAX, i2 = INT_MAX;
    const float h = 1.0f / (float)GS, eps = 1e-3f;
    int R = 0;
    while (true) {
        ++R;
        int xlo = max(cx - R, 0), xhi = min(cx + R, GS - 1);
        int ylo = max(cy - R, 0), yhi = min(cy + R, GS - 1);
        int zlo = max(cz - R, 0), zhi = min(cz + R, GS - 1);
        for (int z = zlo; z <= zhi; ++z) {
            int chz = abs(z - cz);
            for (int y = ylo; y <= yhi; ++y) {
                int chy = abs(y - cy);
                for (int x = xlo; x <= xhi; ++x) {
                    if (R > 1) {                       // skip interior (already scanned)
                        int chx = abs(x - cx);
                        int ch = chx > chy ? chx : chy;
                        if (chz > ch) ch = chz;
                        if (ch < R) continue;
                    }
                    int cc = (z * GS + y) * GS + x;
                    int s = start[cc], n = cnt[cc];
                    for (int t = s; t < s + n; ++t) {
                        int j = sorted_idx[t];
                        if (j == i) continue;
                        float4 p = sorted_pts4[t];
                        float dot = __fmaf_rn(q.z, p.z, __fmaf_rn(q.y, p.y, __fmul_rn(q.x, p.x)));
                        float d2  = __fsub_rn(__fadd_rn(q.w, p.w), __fmul_rn(2.0f, dot));
                        float d   = __fsqrt_rn(fmaxf(d2, 0.0f));
                        bool lt2 = (d < b2) || (d == b2 && j < i2);
                        if (lt2) {
                            bool lt1 = (d < b1) || (d == b1 && j < i1);
                            if (lt1) {
                                b2 = b1; i2 = i1;
                                bool lt0 = (d < b0) || (d == b0 && j < i0);
                                if (lt0) { b1 = b0; i1 = i0; b0 = d; i0 = j; }
                                else     { b1 = d; i1 = j; }
                            } else { b2 = d; i2 = j; }
                        }
                    }
                }
            }
        }
        bool covers_all = (xlo == 0 && ylo == 0 && zlo == 0 &&
                           xhi == GS - 1 && yhi == GS - 1 && zhi == GS - 1);
        if (covers_all) break;
        if (i2 != INT_MAX && b2 < (float)R * h - eps) break;
    }
    out_closest[i * 3 + 0] = (float)i0;
    out_closest[i * 3 + 1] = (float)i1;
    out_closest[i * 3 + 2] = (float)i2;
}

// K3: per-row L2 norm -> 1/max(norm, eps), f64. One wave per row.
__global__ void row_norms(const float* __restrict__ mem_tokens, const float* __restrict__ new_tokens,
                          double* __restrict__ invn) {
    int wave = threadIdx.x >> 6;
    int lane = threadIdx.x & 63;
    int r = blockIdx.x * 4 + wave;
    const float* row = (r < B) ? (mem_tokens + (size_t)r * D) : (new_tokens + (size_t)(r - B) * D);
    float4 v = *(const float4*)(row + lane * 4);
    double s = (double)v.x * (double)v.x + (double)v.y * (double)v.y +
               (double)v.z * (double)v.z + (double)v.w * (double)v.w;
    for (int off = 32; off; off >>= 1) s += __shfl_down(s, off, 64);
    if (lane == 0) {
        double n = sqrt(s);
        if (n < 1e-12) n = 1e-12;
        invn[r] = 1.0 / n;
    }
}

// K4: partial S = sum over rows of normalized tokens (256 blocks x 64 rows)
__global__ void s_partial(const float* __restrict__ mem_tokens, const float* __restrict__ new_tokens,
                          const double* __restrict__ invn, double* __restrict__ S_part) {
    int d  = threadIdx.x;
    int r0 = blockIdx.x * 64;
    double acc = 0.0;
    for (int k = 0; k < 64; ++k) {
        int r = r0 + k;
        const float* row = (r < B) ? (mem_tokens + (size_t)r * D) : (new_tokens + (size_t)(r - B) * D);
        acc += (double)row[d] * invn[r];
    }
    S_part[blockIdx.x * 256 + d] = acc;
}

// K5: reduce 256 partials -> S[256]
__global__ void s_reduce(const double* __restrict__ S_part, double* __restrict__ S) {
    int d = threadIdx.x;
    double s = 0.0;
    for (int b = 0; b < 256; ++b) s += S_part[b * 256 + d];
    S[d] = s;
}

// K6: combined[i] = age_i - invn_i * (t_i . S); also zero rank[]. One wave per row.
__global__ void combined_kernel(const float* __restrict__ mem_tokens, const float* __restrict__ new_tokens,
                                const float* __restrict__ mem_ages,
                                const double* __restrict__ invn, const double* __restrict__ S,
                                double* __restrict__ comb, int* __restrict__ rank) {
    int wave = threadIdx.x >> 6;
    int lane = threadIdx.x & 63;
    int r = blockIdx.x * 4 + wave;
    const float* row = (r < B) ? (mem_tokens + (size_t)r * D) : (new_tokens + (size_t)(r - B) * D);
    float4 v = *(const float4*)(row + lane * 4);
    const double* Sp = S + lane * 4;
    double s = (double)v.x * Sp[0] + (double)v.y * Sp[1] +
               (double)v.z * Sp[2] + (double)v.w * Sp[3];
    for (int off = 32; off; off >>= 1) s += __shfl_down(s, off, 64);
    if (lane == 0) {
        double age = (r < B) ? (double)mem_ages[r] + 1.0 : 0.0;
        comb[r] = age - s * invn[r];
        rank[r] = 0;
    }
}

// K7: stable rank count, 4 consecutive i per thread, split-loop formulation.
__global__ void rank_count(const double* __restrict__ comb, int* __restrict__ rank) {
    __shared__ double cl[JC2];
    int base = (blockIdx.x * 256 + threadIdx.x) * 4;
    int j0   = blockIdx.y * JC2;
    for (int t = threadIdx.x; t < JC2; t += 256) cl[t] = comb[j0 + t];
    __syncthreads();
    double c0 = comb[base + 0], c1 = comb[base + 1];
    double c2 = comb[base + 2], c3 = comb[base + 3];
    int n0 = 0, n1 = 0, n2 = 0, n3 = 0;
    int lo = base - j0;       if (lo < 0) lo = 0; if (lo > JC2) lo = JC2;
    int hi = base + 4 - j0;   if (hi < 0) hi = 0; if (hi > JC2) hi = JC2;
    for (int t = 0; t < lo; ++t) {
        double cj = cl[t];
        n0 += (cj <= c0); n1 += (cj <= c1); n2 += (cj <= c2); n3 += (cj <= c3);
    }
    for (int t = lo; t < hi; ++t) {
        double cj = cl[t];
        int j = j0 + t;
        n0 += (cj < c0) || (cj == c0 && j < base + 0);
        n1 += (cj < c1) || (cj == c1 && j < base + 1);
        n2 += (cj < c2) || (cj == c2 && j < base + 2);
        n3 += (cj < c3) || (cj == c3 && j < base + 3);
    }
    for (int t = hi; t < JC2; ++t) {
        double cj = cl[t];
        n0 += (cj < c0); n1 += (cj < c1); n2 += (cj < c2); n3 += (cj < c3);
    }
    atomicAdd(&rank[base + 0], n0);
    atomicAdd(&rank[base + 1], n1);
    atomicAdd(&rank[base + 2], n2);
    atomicAdd(&rank[base + 3], n3);
}

// K8: scatter kept rows to out[rank[i]], float4-vectorized. One block per source row.
__global__ void gather(const float* __restrict__ mem_keys, const float* __restrict__ mem_tokens,
                       const float* __restrict__ new_tokens, const float* __restrict__ mem_ages,
                       const int* __restrict__ rank,
                       float* __restrict__ out_keys, float* __restrict__ out_tokens,
                       float* __restrict__ out_ages) {
    int r  = blockIdx.x;
    int rk = rank[r];
    if (rk >= B) return;
    int t = threadIdx.x;
    float4* ot = (float4*)(out_tokens + (size_t)rk * D);
    float4* ok = (float4*)(out_keys + (size_t)rk * 3 * D);
    if (r < B) {
        if (t < 64) {
            const float4* st = (const float4*)(mem_tokens + (size_t)r * D);
            ot[t] = st[t];
        } else {
            const float4* sk = (const float4*)(mem_keys + (size_t)r * 3 * D);
            ok[t - 64] = sk[t - 64];
        }
        if (t == 0) out_ages[rk] = mem_ages[r] + 1.0f;
    } else {
        const float4* nt = (const float4*)(new_tokens + (size_t)(r - B) * D);
        float4 v = nt[t & 63];
        if (t < 64) ot[t] = v;
        else        ok[t - 64] = v;
        if (t == 0) out_ages[rk] = 0.0f;
    }
}

extern "C" void kernel_launch(void* const* d_in, const int* in_sizes, int n_in,
                              void* d_out, int out_size, void* d_ws, size_t ws_size,
                              hipStream_t stream) {
    const float* new_tokens = (const float*)d_in[0];  // [8192,256]
    const float* ref_pts    = (const float*)d_in[1];  // [8192,3]
    const float* mem_keys   = (const float*)d_in[2];  // [8192,3,256]
    const float* mem_tokens = (const float*)d_in[3];  // [8192,256]
    const float* mem_ages   = (const float*)d_in[4];  // [8192]

    char* ws = (char*)d_ws;
    float4* sorted_pts4 = (float4*)(ws + 0);
    int*    sorted_idx  = (int*)   (ws + 131072);
    int*    cnt         = (int*)   (ws + 163840);
    int*    start       = (int*)   (ws + 180224);
    int*    cursor      = (int*)   (ws + 196608);
    double* invn        = (double*)(ws + 212992);
    double* S_part      = (double*)(ws + 344064);
    double* S           = (double*)(ws + 868352);
    double* comb        = (double*)(ws + 870400);
    int*    rank        = (int*)   (ws + 1001472);

    float* out = (float*)d_out;
    float* out_keys    = out;                       // 8192*3*256 = 6291456
    float* out_tokens  = out + 6291456;             // 8192*256   = 2097152
    float* out_ages    = out + 6291456 + 2097152;   // 8192
    float* out_closest = out_ages + 8192;           // 8192*3 (written as float)

    zero_cnt<<<NC / 256, 256, 0, stream>>>(cnt);
    grid_hist<<<B / 256, 256, 0, stream>>>(ref_pts, cnt);
    grid_scan<<<1, 256, 0, stream>>>(cnt, start, cursor);
    grid_scatter<<<B / 256, 256, 0, stream>>>(ref_pts, cursor, sorted_pts4, sorted_idx);
    knn_grid<<<B / 256, 256, 0, stream>>>(sorted_pts4, sorted_idx, start, cnt, out_closest);

    row_norms<<<TOT / 4, 256, 0, stream>>>(mem_tokens, new_tokens, invn);
    s_partial<<<256, 256, 0, stream>>>(mem_tokens, new_tokens, invn, S_part);
    s_reduce<<<1, 256, 0, stream>>>(S_part, S);
    combined_kernel<<<TOT / 4, 256, 0, stream>>>(mem_tokens, new_tokens, mem_ages, invn, S, comb, rank);
    rank_count<<<dim3(TOT / (256 * 4), TOT / JC2), 256, 0, stream>>>(comb, rank);
    gather<<<TOT, 256, 0, stream>>>(mem_keys, mem_tokens, new_tokens, mem_ages, rank,
                                    out_keys, out_tokens, out_ages);
}

// Round 5
// 114.287 us; speedup vs baseline: 2.2590x; 2.2590x over previous
//
#include <hip/hip_runtime.h>
#include <climits>

#define B   8192
#define D   256
#define TOT 16384
#define GS  16
#define NC  (GS * GS * GS)   // 4096 cells
#define JC2 256

// ---------------- workspace layout (bytes) ----------------
// sorted_pts4 : f32x4 [B]   @ 0        (131072)
// sorted_idx  : i32  [B]    @ 131072   (32768)
// cnt         : i32  [NC]   @ 163840   (16384)
// start       : i32  [NC]   @ 180224   (16384)
// cursor      : i32  [NC]   @ 196608   (16384)
// invn        : f64  [TOT]  @ 212992   (131072)
// S_part      : f64  [65536]@ 344064   (524288)
// S           : f64  [256]  @ 868352   (2048)
// comb        : f64  [TOT]  @ 870400   (131072)
// rank        : i32  [TOT]  @ 1001472  (65536)
// total ~1.07 MB

__device__ __forceinline__ int clamp_cell(float x) {
    int c = (int)(x * (float)GS);
    if (c < 0) c = 0;
    if (c > GS - 1) c = GS - 1;
    return c;
}

// G0: zero cell counts
__global__ void zero_cnt(int* __restrict__ cnt) {
    cnt[blockIdx.x * 256 + threadIdx.x] = 0;
}

// G1: histogram of cell ids
__global__ void grid_hist(const float* __restrict__ ref, int* __restrict__ cnt) {
    int i = blockIdx.x * 256 + threadIdx.x;
    int cx = clamp_cell(ref[i * 3 + 0]);
    int cy = clamp_cell(ref[i * 3 + 1]);
    int cz = clamp_cell(ref[i * 3 + 2]);
    atomicAdd(&cnt[(cz * GS + cy) * GS + cx], 1);
}

// G2: exclusive scan of 4096 counts -> start[], cursor[]  (single block, 256 thr)
__global__ void grid_scan(const int* __restrict__ cnt, int* __restrict__ start,
                          int* __restrict__ cursor) {
    __shared__ int part[256];
    int t = threadIdx.x;
    int s = 0;
    for (int k = 0; k < 16; ++k) s += cnt[t * 16 + k];
    part[t] = s;
    __syncthreads();
    if (t == 0) {
        int acc = 0;
        for (int q = 0; q < 256; ++q) { int v = part[q]; part[q] = acc; acc += v; }
    }
    __syncthreads();
    int base = part[t];
    for (int k = 0; k < 16; ++k) {
        int c = t * 16 + k;
        int v = cnt[c];
        start[c] = base; cursor[c] = base;
        base += v;
    }
}

// G3: scatter points into cell-sorted order, precompute sq = (x*x+y*y)+z*z (ref-exact)
__global__ void grid_scatter(const float* __restrict__ ref, int* __restrict__ cursor,
                             float4* __restrict__ sorted_pts4, int* __restrict__ sorted_idx) {
    int i = blockIdx.x * 256 + threadIdx.x;
    float x = ref[i * 3 + 0], y = ref[i * 3 + 1], z = ref[i * 3 + 2];
    int c = (clamp_cell(z) * GS + clamp_cell(y)) * GS + clamp_cell(x);
    float sq = __fadd_rn(__fadd_rn(__fmul_rn(x, x), __fmul_rn(y, y)), __fmul_rn(z, z));
    int pos = atomicAdd(&cursor[c], 1);
    sorted_pts4[pos] = make_float4(x, y, z, sq);
    sorted_idx[pos]  = i;
}

// G4: wave-per-query grid kNN. Wave w handles the w-th cell-sorted point.
// Lane r owns cell-row r of the (2R+1)^2 rows of the radius-R block (a row =
// contiguous x-run of cells => one contiguous span of the sorted array).
// Each lane keeps a lexicographic (d, idx) top-3 of its candidates; then 3
// rounds of {wave-wide shfl_xor min, remove winner} give the exact top-3.
// Examined pairs use the EXACT verified f32 reference sequence:
//   dot = fma(qz,pz, fma(qy,py, qx*px)); d2 = (qsq+psq) - 2*dot; d = sqrt_rn(max(d2,0)).
// Retry with R+1 rescans the whole block with reset lists (no dup hazard).
// Stop when 3 found and b2 < R*h - 1e-3 (unexamined points have ref-d
// >= R*h - ~1e-5) => selection identical to the full O(N^2) scan.
__global__ void knn_grid_wave(const float4* __restrict__ sorted_pts4,
                              const int* __restrict__ sorted_idx,
                              const int* __restrict__ start, const int* __restrict__ cnt,
                              float* __restrict__ out_closest) {
    int wave = threadIdx.x >> 6;
    int lane = threadIdx.x & 63;
    int k = blockIdx.x * 4 + wave;
    float4 q = sorted_pts4[k];
    int i = sorted_idx[k];
    int cx = clamp_cell(q.x), cy = clamp_cell(q.y), cz = clamp_cell(q.z);
    const float h = 1.0f / (float)GS, eps = 1e-3f;
    float w0 = INFINITY, w1 = INFINITY, w2 = INFINITY;
    int   wi0 = INT_MAX, wi1 = INT_MAX, wi2 = INT_MAX;
    int R = 0;
    while (true) {
        ++R;
        float b0 = INFINITY, b1 = INFINITY, b2 = INFINITY;
        int   i0 = INT_MAX, i1 = INT_MAX, i2 = INT_MAX;
        int xlo = max(cx - R, 0), xhi = min(cx + R, GS - 1);
        int ylo = max(cy - R, 0), yhi = min(cy + R, GS - 1);
        int zlo = max(cz - R, 0), zhi = min(cz + R, GS - 1);
        int ny = yhi - ylo + 1;
        int rows = ny * (zhi - zlo + 1);
        for (int r = lane; r < rows; r += 64) {
            int z = zlo + r / ny;
            int y = ylo + r % ny;
            int crow = (z * GS + y) * GS;
            int s = start[crow + xlo];
            int e = start[crow + xhi] + cnt[crow + xhi];
            for (int t = s; t < e; ++t) {
                int j = sorted_idx[t];
                if (j == i) continue;
                float4 p = sorted_pts4[t];
                float dot = __fmaf_rn(q.z, p.z, __fmaf_rn(q.y, p.y, __fmul_rn(q.x, p.x)));
                float d2  = __fsub_rn(__fadd_rn(q.w, p.w), __fmul_rn(2.0f, dot));
                float d   = __fsqrt_rn(fmaxf(d2, 0.0f));
                bool lt2 = (d < b2) || (d == b2 && j < i2);
                if (lt2) {
                    bool lt1 = (d < b1) || (d == b1 && j < i1);
                    if (lt1) {
                        b2 = b1; i2 = i1;
                        bool lt0 = (d < b0) || (d == b0 && j < i0);
                        if (lt0) { b1 = b0; i1 = i0; b0 = d; i0 = j; }
                        else     { b1 = d; i1 = j; }
                    } else { b2 = d; i2 = j; }
                }
            }
        }
        // 3 selection rounds: wave-wide lexicographic min + removal (idx unique per lane)
        #pragma unroll
        for (int s = 0; s < 3; ++s) {
            float d = b0; int ix = i0;
            for (int off = 32; off; off >>= 1) {
                float od = __shfl_xor(d, off, 64);
                int   oi = __shfl_xor(ix, off, 64);
                if (od < d || (od == d && oi < ix)) { d = od; ix = oi; }
            }
            if (s == 0) { w0 = d; wi0 = ix; }
            else if (s == 1) { w1 = d; wi1 = ix; }
            else { w2 = d; wi2 = ix; }
            if (i0 == ix) { b0 = b1; i0 = i1; b1 = b2; i1 = i2; b2 = INFINITY; i2 = INT_MAX; }
        }
        bool covers = (xlo == 0 && ylo == 0 && zlo == 0 &&
                       xhi == GS - 1 && yhi == GS - 1 && zhi == GS - 1);
        if (covers) break;
        if (wi2 != INT_MAX && w2 < (float)R * h - eps) break;
    }
    if (lane == 0) {
        out_closest[i * 3 + 0] = (float)wi0;
        out_closest[i * 3 + 1] = (float)wi1;
        out_closest[i * 3 + 2] = (float)wi2;
    }
}

// K3: per-row L2 norm -> 1/max(norm, eps), f64. One wave per row.
__global__ void row_norms(const float* __restrict__ mem_tokens, const float* __restrict__ new_tokens,
                          double* __restrict__ invn) {
    int wave = threadIdx.x >> 6;
    int lane = threadIdx.x & 63;
    int r = blockIdx.x * 4 + wave;
    const float* row = (r < B) ? (mem_tokens + (size_t)r * D) : (new_tokens + (size_t)(r - B) * D);
    float4 v = *(const float4*)(row + lane * 4);
    double s = (double)v.x * (double)v.x + (double)v.y * (double)v.y +
               (double)v.z * (double)v.z + (double)v.w * (double)v.w;
    for (int off = 32; off; off >>= 1) s += __shfl_down(s, off, 64);
    if (lane == 0) {
        double n = sqrt(s);
        if (n < 1e-12) n = 1e-12;
        invn[r] = 1.0 / n;
    }
}

// K4: partial S = sum over rows of normalized tokens (256 blocks x 64 rows)
__global__ void s_partial(const float* __restrict__ mem_tokens, const float* __restrict__ new_tokens,
                          const double* __restrict__ invn, double* __restrict__ S_part) {
    int d  = threadIdx.x;
    int r0 = blockIdx.x * 64;
    double acc = 0.0;
    for (int k = 0; k < 64; ++k) {
        int r = r0 + k;
        const float* row = (r < B) ? (mem_tokens + (size_t)r * D) : (new_tokens + (size_t)(r - B) * D);
        acc += (double)row[d] * invn[r];
    }
    S_part[blockIdx.x * 256 + d] = acc;
}

// K5: reduce 256 partials -> S[256]
__global__ void s_reduce(const double* __restrict__ S_part, double* __restrict__ S) {
    int d = threadIdx.x;
    double s = 0.0;
    for (int b = 0; b < 256; ++b) s += S_part[b * 256 + d];
    S[d] = s;
}

// K6: combined[i] = age_i - invn_i * (t_i . S); also zero rank[]. One wave per row.
__global__ void combined_kernel(const float* __restrict__ mem_tokens, const float* __restrict__ new_tokens,
                                const float* __restrict__ mem_ages,
                                const double* __restrict__ invn, const double* __restrict__ S,
                                double* __restrict__ comb, int* __restrict__ rank) {
    int wave = threadIdx.x >> 6;
    int lane = threadIdx.x & 63;
    int r = blockIdx.x * 4 + wave;
    const float* row = (r < B) ? (mem_tokens + (size_t)r * D) : (new_tokens + (size_t)(r - B) * D);
    float4 v = *(const float4*)(row + lane * 4);
    const double* Sp = S + lane * 4;
    double s = (double)v.x * Sp[0] + (double)v.y * Sp[1] +
               (double)v.z * Sp[2] + (double)v.w * Sp[3];
    for (int off = 32; off; off >>= 1) s += __shfl_down(s, off, 64);
    if (lane == 0) {
        double age = (r < B) ? (double)mem_ages[r] + 1.0 : 0.0;
        comb[r] = age - s * invn[r];
        rank[r] = 0;
    }
}

// K7: stable rank count, 4 consecutive i per thread, split-loop formulation.
__global__ void rank_count(const double* __restrict__ comb, int* __restrict__ rank) {
    __shared__ double cl[JC2];
    int base = (blockIdx.x * 256 + threadIdx.x) * 4;
    int j0   = blockIdx.y * JC2;
    for (int t = threadIdx.x; t < JC2; t += 256) cl[t] = comb[j0 + t];
    __syncthreads();
    double c0 = comb[base + 0], c1 = comb[base + 1];
    double c2 = comb[base + 2], c3 = comb[base + 3];
    int n0 = 0, n1 = 0, n2 = 0, n3 = 0;
    int lo = base - j0;       if (lo < 0) lo = 0; if (lo > JC2) lo = JC2;
    int hi = base + 4 - j0;   if (hi < 0) hi = 0; if (hi > JC2) hi = JC2;
    for (int t = 0; t < lo; ++t) {
        double cj = cl[t];
        n0 += (cj <= c0); n1 += (cj <= c1); n2 += (cj <= c2); n3 += (cj <= c3);
    }
    for (int t = lo; t < hi; ++t) {
        double cj = cl[t];
        int j = j0 + t;
        n0 += (cj < c0) || (cj == c0 && j < base + 0);
        n1 += (cj < c1) || (cj == c1 && j < base + 1);
        n2 += (cj < c2) || (cj == c2 && j < base + 2);
        n3 += (cj < c3) || (cj == c3 && j < base + 3);
    }
    for (int t = hi; t < JC2; ++t) {
        double cj = cl[t];
        n0 += (cj < c0); n1 += (cj < c1); n2 += (cj < c2); n3 += (cj < c3);
    }
    atomicAdd(&rank[base + 0], n0);
    atomicAdd(&rank[base + 1], n1);
    atomicAdd(&rank[base + 2], n2);
    atomicAdd(&rank[base + 3], n3);
}

// K8: scatter kept rows to out[rank[i]], float4-vectorized. One block per source row.
__global__ void gather(const float* __restrict__ mem_keys, const float* __restrict__ mem_tokens,
                       const float* __restrict__ new_tokens, const float* __restrict__ mem_ages,
                       const int* __restrict__ rank,
                       float* __restrict__ out_keys, float* __restrict__ out_tokens,
                       float* __restrict__ out_ages) {
    int r  = blockIdx.x;
    int rk = rank[r];
    if (rk >= B) return;
    int t = threadIdx.x;
    float4* ot = (float4*)(out_tokens + (size_t)rk * D);
    float4* ok = (float4*)(out_keys + (size_t)rk * 3 * D);
    if (r < B) {
        if (t < 64) {
            const float4* st = (const float4*)(mem_tokens + (size_t)r * D);
            ot[t] = st[t];
        } else {
            const float4* sk = (const float4*)(mem_keys + (size_t)r * 3 * D);
            ok[t - 64] = sk[t - 64];
        }
        if (t == 0) out_ages[rk] = mem_ages[r] + 1.0f;
    } else {
        const float4* nt = (const float4*)(new_tokens + (size_t)(r - B) * D);
        float4 v = nt[t & 63];
        if (t < 64) ot[t] = v;
        else        ok[t - 64] = v;
        if (t == 0) out_ages[rk] = 0.0f;
    }
}

extern "C" void kernel_launch(void* const* d_in, const int* in_sizes, int n_in,
                              void* d_out, int out_size, void* d_ws, size_t ws_size,
                              hipStream_t stream) {
    const float* new_tokens = (const float*)d_in[0];  // [8192,256]
    const float* ref_pts    = (const float*)d_in[1];  // [8192,3]
    const float* mem_keys   = (const float*)d_in[2];  // [8192,3,256]
    const float* mem_tokens = (const float*)d_in[3];  // [8192,256]
    const float* mem_ages   = (const float*)d_in[4];  // [8192]

    char* ws = (char*)d_ws;
    float4* sorted_pts4 = (float4*)(ws + 0);
    int*    sorted_idx  = (int*)   (ws + 131072);
    int*    cnt         = (int*)   (ws + 163840);
    int*    start       = (int*)   (ws + 180224);
    int*    cursor      = (int*)   (ws + 196608);
    double* invn        = (double*)(ws + 212992);
    double* S_part      = (double*)(ws + 344064);
    double* S           = (double*)(ws + 868352);
    double* comb        = (double*)(ws + 870400);
    int*    rank        = (int*)   (ws + 1001472);

    float* out = (float*)d_out;
    float* out_keys    = out;                       // 8192*3*256 = 6291456
    float* out_tokens  = out + 6291456;             // 8192*256   = 2097152
    float* out_ages    = out + 6291456 + 2097152;   // 8192
    float* out_closest = out_ages + 8192;           // 8192*3 (written as float)

    zero_cnt<<<NC / 256, 256, 0, stream>>>(cnt);
    grid_hist<<<B / 256, 256, 0, stream>>>(ref_pts, cnt);
    grid_scan<<<1, 256, 0, stream>>>(cnt, start, cursor);
    grid_scatter<<<B / 256, 256, 0, stream>>>(ref_pts, cursor, sorted_pts4, sorted_idx);
    knn_grid_wave<<<B / 4, 256, 0, stream>>>(sorted_pts4, sorted_idx, start, cnt, out_closest);

    row_norms<<<TOT / 4, 256, 0, stream>>>(mem_tokens, new_tokens, invn);
    s_partial<<<256, 256, 0, stream>>>(mem_tokens, new_tokens, invn, S_part);
    s_reduce<<<1, 256, 0, stream>>>(S_part, S);
    combined_kernel<<<TOT / 4, 256, 0, stream>>>(mem_tokens, new_tokens, mem_ages, invn, S, comb, rank);
    rank_count<<<dim3(TOT / (256 * 4), TOT / JC2), 256, 0, stream>>>(comb, rank);
    gather<<<TOT, 256, 0, stream>>>(mem_keys, mem_tokens, new_tokens, mem_ages, rank,
                                    out_keys, out_tokens, out_ages);
}

// Round 6
// 112.340 us; speedup vs baseline: 2.2982x; 1.0173x over previous
//
#include <hip/hip_runtime.h>
#include <climits>

#define B   8192
#define D   256
#define TOT 16384
#define GS  16
#define NC  (GS * GS * GS)   // 4096 cells
#define NCH 32               // rank j-chunks
#define JCW (TOT / NCH)      // 512
#define RPB 128              // rows per block in norms_spart

// ---------------- workspace layout (bytes) ----------------
// sorted_pts4 : f32x4 [B]        @ 0        (131072)
// sorted_idx  : i32  [B]         @ 131072   (32768)
// cnt         : i32  [NC]        @ 163840   (16384)
// start       : i32  [NC]        @ 180224   (16384)
// cursor      : i32  [NC]        @ 196608   (16384)
// invn        : f64  [TOT]       @ 212992   (131072)
// S_part      : f64  [128*256]   @ 344064   (262144)
// S           : f64  [256]       @ 606208   (2048)
// comb        : f64  [TOT]       @ 608256   (131072)
// partial     : i32  [NCH*TOT]   @ 739328   (2097152)
// rank        : i32  [TOT]       @ 2836480  (65536)
// total ~2.9 MB

__device__ __forceinline__ int clamp_cell(float x) {
    int c = (int)(x * (float)GS);
    if (c < 0) c = 0;
    if (c > GS - 1) c = GS - 1;
    return c;
}

// G0: zero cell counts
__global__ void zero_cnt(int* __restrict__ cnt) {
    cnt[blockIdx.x * 256 + threadIdx.x] = 0;
}

// G1: histogram of cell ids
__global__ void grid_hist(const float* __restrict__ ref, int* __restrict__ cnt) {
    int i = blockIdx.x * 256 + threadIdx.x;
    int cx = clamp_cell(ref[i * 3 + 0]);
    int cy = clamp_cell(ref[i * 3 + 1]);
    int cz = clamp_cell(ref[i * 3 + 2]);
    atomicAdd(&cnt[(cz * GS + cy) * GS + cx], 1);
}

// G2: exclusive scan of 4096 counts -> start[], cursor[]  (single block, 256 thr)
__global__ void grid_scan(const int* __restrict__ cnt, int* __restrict__ start,
                          int* __restrict__ cursor) {
    __shared__ int part[256];
    int t = threadIdx.x;
    int s = 0;
    for (int k = 0; k < 16; ++k) s += cnt[t * 16 + k];
    part[t] = s;
    __syncthreads();
    if (t == 0) {
        int acc = 0;
        for (int q = 0; q < 256; ++q) { int v = part[q]; part[q] = acc; acc += v; }
    }
    __syncthreads();
    int base = part[t];
    for (int k = 0; k < 16; ++k) {
        int c = t * 16 + k;
        int v = cnt[c];
        start[c] = base; cursor[c] = base;
        base += v;
    }
}

// G3: scatter points into cell-sorted order, precompute sq = (x*x+y*y)+z*z (ref-exact)
__global__ void grid_scatter(const float* __restrict__ ref, int* __restrict__ cursor,
                             float4* __restrict__ sorted_pts4, int* __restrict__ sorted_idx) {
    int i = blockIdx.x * 256 + threadIdx.x;
    float x = ref[i * 3 + 0], y = ref[i * 3 + 1], z = ref[i * 3 + 2];
    int c = (clamp_cell(z) * GS + clamp_cell(y)) * GS + clamp_cell(x);
    float sq = __fadd_rn(__fadd_rn(__fmul_rn(x, x), __fmul_rn(y, y)), __fmul_rn(z, z));
    int pos = atomicAdd(&cursor[c], 1);
    sorted_pts4[pos] = make_float4(x, y, z, sq);
    sorted_idx[pos]  = i;
}

// G4: wave-per-query grid kNN (verified round 5). Exact f32 reference arithmetic,
// lexicographic (d, idx) selection, ring-stop margin.
__global__ void knn_grid_wave(const float4* __restrict__ sorted_pts4,
                              const int* __restrict__ sorted_idx,
                              const int* __restrict__ start, const int* __restrict__ cnt,
                              float* __restrict__ out_closest) {
    int wave = threadIdx.x >> 6;
    int lane = threadIdx.x & 63;
    int k = blockIdx.x * 4 + wave;
    float4 q = sorted_pts4[k];
    int i = sorted_idx[k];
    int cx = clamp_cell(q.x), cy = clamp_cell(q.y), cz = clamp_cell(q.z);
    const float h = 1.0f / (float)GS, eps = 1e-3f;
    float w0 = INFINITY, w1 = INFINITY, w2 = INFINITY;
    int   wi0 = INT_MAX, wi1 = INT_MAX, wi2 = INT_MAX;
    int R = 0;
    while (true) {
        ++R;
        float b0 = INFINITY, b1 = INFINITY, b2 = INFINITY;
        int   i0 = INT_MAX, i1 = INT_MAX, i2 = INT_MAX;
        int xlo = max(cx - R, 0), xhi = min(cx + R, GS - 1);
        int ylo = max(cy - R, 0), yhi = min(cy + R, GS - 1);
        int zlo = max(cz - R, 0), zhi = min(cz + R, GS - 1);
        int ny = yhi - ylo + 1;
        int rows = ny * (zhi - zlo + 1);
        for (int r = lane; r < rows; r += 64) {
            int z = zlo + r / ny;
            int y = ylo + r % ny;
            int crow = (z * GS + y) * GS;
            int s = start[crow + xlo];
            int e = start[crow + xhi] + cnt[crow + xhi];
            for (int t = s; t < e; ++t) {
                int j = sorted_idx[t];
                if (j == i) continue;
                float4 p = sorted_pts4[t];
                float dot = __fmaf_rn(q.z, p.z, __fmaf_rn(q.y, p.y, __fmul_rn(q.x, p.x)));
                float d2  = __fsub_rn(__fadd_rn(q.w, p.w), __fmul_rn(2.0f, dot));
                float d   = __fsqrt_rn(fmaxf(d2, 0.0f));
                bool lt2 = (d < b2) || (d == b2 && j < i2);
                if (lt2) {
                    bool lt1 = (d < b1) || (d == b1 && j < i1);
                    if (lt1) {
                        b2 = b1; i2 = i1;
                        bool lt0 = (d < b0) || (d == b0 && j < i0);
                        if (lt0) { b1 = b0; i1 = i0; b0 = d; i0 = j; }
                        else     { b1 = d; i1 = j; }
                    } else { b2 = d; i2 = j; }
                }
            }
        }
        #pragma unroll
        for (int s = 0; s < 3; ++s) {
            float d = b0; int ix = i0;
            for (int off = 32; off; off >>= 1) {
                float od = __shfl_xor(d, off, 64);
                int   oi = __shfl_xor(ix, off, 64);
                if (od < d || (od == d && oi < ix)) { d = od; ix = oi; }
            }
            if (s == 0) { w0 = d; wi0 = ix; }
            else if (s == 1) { w1 = d; wi1 = ix; }
            else { w2 = d; wi2 = ix; }
            if (i0 == ix) { b0 = b1; i0 = i1; b1 = b2; i1 = i2; b2 = INFINITY; i2 = INT_MAX; }
        }
        bool covers = (xlo == 0 && ylo == 0 && zlo == 0 &&
                       xhi == GS - 1 && yhi == GS - 1 && zhi == GS - 1);
        if (covers) break;
        if (wi2 != INT_MAX && w2 < (float)R * h - eps) break;
    }
    if (lane == 0) {
        out_closest[i * 3 + 0] = (float)wi0;
        out_closest[i * 3 + 1] = (float)wi1;
        out_closest[i * 3 + 2] = (float)wi2;
    }
}

// K3+K4 fused: per-row 1/norm AND per-block partial S in one 16 MB pass.
// Wave handles rows rbase+wave, +4, ...; butterfly shfl_xor gives every lane
// the row's sum-of-squares; lanes accumulate inv*row into 4 f64 registers.
__global__ void norms_spart(const float* __restrict__ mem_tokens,
                            const float* __restrict__ new_tokens,
                            double* __restrict__ invn, double* __restrict__ S_part) {
    __shared__ double sacc[4][256];
    int wave = threadIdx.x >> 6;
    int lane = threadIdx.x & 63;
    int rbase = blockIdx.x * RPB;
    double a0 = 0.0, a1 = 0.0, a2 = 0.0, a3 = 0.0;
    for (int k = wave; k < RPB; k += 4) {
        int r = rbase + k;
        const float* row = (r < B) ? (mem_tokens + (size_t)r * D) : (new_tokens + (size_t)(r - B) * D);
        float4 v = *(const float4*)(row + lane * 4);
        double s = (double)v.x * (double)v.x + (double)v.y * (double)v.y +
                   (double)v.z * (double)v.z + (double)v.w * (double)v.w;
        for (int off = 32; off; off >>= 1) s += __shfl_xor(s, off, 64);
        double n = sqrt(s);
        if (n < 1e-12) n = 1e-12;
        double inv = 1.0 / n;
        if (lane == 0) invn[r] = inv;
        a0 += (double)v.x * inv; a1 += (double)v.y * inv;
        a2 += (double)v.z * inv; a3 += (double)v.w * inv;
    }
    sacc[wave][lane * 4 + 0] = a0;
    sacc[wave][lane * 4 + 1] = a1;
    sacc[wave][lane * 4 + 2] = a2;
    sacc[wave][lane * 4 + 3] = a3;
    __syncthreads();
    int d = threadIdx.x;
    S_part[blockIdx.x * 256 + d] = sacc[0][d] + sacc[1][d] + sacc[2][d] + sacc[3][d];
}

// K5: reduce 128 partials -> S[256]
__global__ void s_reduce(const double* __restrict__ S_part, double* __restrict__ S) {
    int d = threadIdx.x;
    double s = 0.0;
    for (int b = 0; b < TOT / RPB; ++b) s += S_part[b * 256 + d];
    S[d] = s;
}

// K6: combined[i] = age_i - invn_i * (t_i . S). One wave per row.
__global__ void combined_kernel(const float* __restrict__ mem_tokens, const float* __restrict__ new_tokens,
                                const float* __restrict__ mem_ages,
                                const double* __restrict__ invn, const double* __restrict__ S,
                                double* __restrict__ comb) {
    int wave = threadIdx.x >> 6;
    int lane = threadIdx.x & 63;
    int r = blockIdx.x * 4 + wave;
    const float* row = (r < B) ? (mem_tokens + (size_t)r * D) : (new_tokens + (size_t)(r - B) * D);
    float4 v = *(const float4*)(row + lane * 4);
    const double* Sp = S + lane * 4;
    double s = (double)v.x * Sp[0] + (double)v.y * Sp[1] +
               (double)v.z * Sp[2] + (double)v.w * Sp[3];
    for (int off = 32; off; off >>= 1) s += __shfl_down(s, off, 64);
    if (lane == 0) {
        double age = (r < B) ? (double)mem_ages[r] + 1.0 : 0.0;
        comb[r] = age - s * invn[r];
    }
}

// K7: stable rank count, NO atomics. 4 consecutive i per thread; per-chunk
// counts go to partial[chunk][i] (contiguous int4 store). Split-loop keeps
// the exact lexicographic order; straddle window (<=4 iters) does tie-break.
__global__ void rank_count(const double* __restrict__ comb, int* __restrict__ partial) {
    __shared__ double cl[JCW];
    int tid  = threadIdx.x;
    int base = (blockIdx.x * 256 + tid) * 4;
    int j0   = blockIdx.y * JCW;
    for (int t = tid; t < JCW; t += 256) cl[t] = comb[j0 + t];
    __syncthreads();
    double c0 = comb[base + 0], c1 = comb[base + 1];
    double c2 = comb[base + 2], c3 = comb[base + 3];
    int n0 = 0, n1 = 0, n2 = 0, n3 = 0;
    int lo = base - j0;       if (lo < 0) lo = 0; if (lo > JCW) lo = JCW;
    int hi = base + 4 - j0;   if (hi < 0) hi = 0; if (hi > JCW) hi = JCW;
    #pragma unroll 8
    for (int t = 0; t < lo; ++t) {           // j < all i: count cj <= ci
        double cj = cl[t];
        n0 += (cj <= c0); n1 += (cj <= c1); n2 += (cj <= c2); n3 += (cj <= c3);
    }
    for (int t = lo; t < hi; ++t) {          // straddle: exact tie-break
        double cj = cl[t];
        int j = j0 + t;
        n0 += (cj < c0) || (cj == c0 && j < base + 0);
        n1 += (cj < c1) || (cj == c1 && j < base + 1);
        n2 += (cj < c2) || (cj == c2 && j < base + 2);
        n3 += (cj < c3) || (cj == c3 && j < base + 3);
    }
    #pragma unroll 8
    for (int t = hi; t < JCW; ++t) {         // j > all i: count cj < ci
        double cj = cl[t];
        n0 += (cj < c0); n1 += (cj < c1); n2 += (cj < c2); n3 += (cj < c3);
    }
    *(int4*)&partial[blockIdx.y * TOT + base] = make_int4(n0, n1, n2, n3);
}

// K7b: rank[i] = sum over chunks of partial[ch][i]
__global__ void rank_reduce(const int* __restrict__ partial, int* __restrict__ rank) {
    int i = blockIdx.x * 256 + threadIdx.x;
    int s = 0;
    #pragma unroll
    for (int ch = 0; ch < NCH; ++ch) s += partial[ch * TOT + i];
    rank[i] = s;
}

// K8: scatter kept rows to out[rank[i]], float4-vectorized. One block per source row.
__global__ void gather(const float* __restrict__ mem_keys, const float* __restrict__ mem_tokens,
                       const float* __restrict__ new_tokens, const float* __restrict__ mem_ages,
                       const int* __restrict__ rank,
                       float* __restrict__ out_keys, float* __restrict__ out_tokens,
                       float* __restrict__ out_ages) {
    int r  = blockIdx.x;
    int rk = rank[r];
    if (rk >= B) return;
    int t = threadIdx.x;
    float4* ot = (float4*)(out_tokens + (size_t)rk * D);
    float4* ok = (float4*)(out_keys + (size_t)rk * 3 * D);
    if (r < B) {
        if (t < 64) {
            const float4* st = (const float4*)(mem_tokens + (size_t)r * D);
            ot[t] = st[t];
        } else {
            const float4* sk = (const float4*)(mem_keys + (size_t)r * 3 * D);
            ok[t - 64] = sk[t - 64];
        }
        if (t == 0) out_ages[rk] = mem_ages[r] + 1.0f;
    } else {
        const float4* nt = (const float4*)(new_tokens + (size_t)(r - B) * D);
        float4 v = nt[t & 63];
        if (t < 64) ot[t] = v;
        else        ok[t - 64] = v;
        if (t == 0) out_ages[rk] = 0.0f;
    }
}

extern "C" void kernel_launch(void* const* d_in, const int* in_sizes, int n_in,
                              void* d_out, int out_size, void* d_ws, size_t ws_size,
                              hipStream_t stream) {
    const float* new_tokens = (const float*)d_in[0];  // [8192,256]
    const float* ref_pts    = (const float*)d_in[1];  // [8192,3]
    const float* mem_keys   = (const float*)d_in[2];  // [8192,3,256]
    const float* mem_tokens = (const float*)d_in[3];  // [8192,256]
    const float* mem_ages   = (const float*)d_in[4];  // [8192]

    char* ws = (char*)d_ws;
    float4* sorted_pts4 = (float4*)(ws + 0);
    int*    sorted_idx  = (int*)   (ws + 131072);
    int*    cnt         = (int*)   (ws + 163840);
    int*    start       = (int*)   (ws + 180224);
    int*    cursor      = (int*)   (ws + 196608);
    double* invn        = (double*)(ws + 212992);
    double* S_part      = (double*)(ws + 344064);
    double* S           = (double*)(ws + 606208);
    double* comb        = (double*)(ws + 608256);
    int*    partial     = (int*)   (ws + 739328);
    int*    rank        = (int*)   (ws + 2836480);

    float* out = (float*)d_out;
    float* out_keys    = out;                       // 8192*3*256 = 6291456
    float* out_tokens  = out + 6291456;             // 8192*256   = 2097152
    float* out_ages    = out + 6291456 + 2097152;   // 8192
    float* out_closest = out_ages + 8192;           // 8192*3 (written as float)

    zero_cnt<<<NC / 256, 256, 0, stream>>>(cnt);
    grid_hist<<<B / 256, 256, 0, stream>>>(ref_pts, cnt);
    grid_scan<<<1, 256, 0, stream>>>(cnt, start, cursor);
    grid_scatter<<<B / 256, 256, 0, stream>>>(ref_pts, cursor, sorted_pts4, sorted_idx);
    knn_grid_wave<<<B / 4, 256, 0, stream>>>(sorted_pts4, sorted_idx, start, cnt, out_closest);

    norms_spart<<<TOT / RPB, 256, 0, stream>>>(mem_tokens, new_tokens, invn, S_part);
    s_reduce<<<1, 256, 0, stream>>>(S_part, S);
    combined_kernel<<<TOT / 4, 256, 0, stream>>>(mem_tokens, new_tokens, mem_ages, invn, S, comb);
    rank_count<<<dim3(TOT / (256 * 4), NCH), 256, 0, stream>>>(comb, partial);
    rank_reduce<<<TOT / 256, 256, 0, stream>>>(partial, rank);
    gather<<<TOT, 256, 0, stream>>>(mem_keys, mem_tokens, new_tokens, mem_ages, rank,
                                    out_keys, out_tokens, out_ages);
}